// Round 14
// baseline (334.537 us; speedup 1.0000x reference)
//
#include <hip/hip_runtime.h>
#include <math.h>

// Problem constants (match reference)
#define BB 1024
#define TT 2048
#define II 2
#define HH 64

// ---- Hybrid DPP + packed-f32 MAC -------------------------------------------
// Per step, the 64-term dot splits:
//  * OWN HALF (32 cols) via DPP row_newbcast on v80/v81: after one
//    v_permlane16_swap of dual h-copies, rows 0,1 of (v80,v81) broadcast
//    groups {0,1} and rows 2,3 groups {2,3} (exact convention PROBED in the
//    prologue; weight banks loaded from per-lane probed column bases).
//    32 fmacs, zero DS traffic, and they fill the LDS turnaround window.
//  * OTHER HALF (32 cols) via LDS broadcast: h written once (lane k -> 4k),
//    8 ds_read_b128 at per-lane half-base (2-line split = free), 16
//    v_pk_fma_f32. DS ops/step: 9 (was 17 in r13) -> DS pipe off the
//    critical path.
#define FM(a,c,w,r) "v_fmac_f32 " a ", " c ", " w " row_newbcast:" r "\n\t"
#define MU(a,c,w,r) "v_mul_f32 "  a ", " c ", " w " row_newbcast:" r "\n\t"

// DPP quarter A: 16 cols starting at probed base gA (weights v12-27)
#define QA \
 MU("v76","v80","v12","0")  MU("v77","v80","v13","1")  MU("v78","v80","v14","2")  MU("v79","v80","v15","3") \
 FM("v76","v80","v16","4")  FM("v77","v80","v17","5")  FM("v78","v80","v18","6")  FM("v79","v80","v19","7") \
 FM("v76","v80","v20","8")  FM("v77","v80","v21","9")  FM("v78","v80","v22","10") FM("v79","v80","v23","11") \
 FM("v76","v80","v24","12") FM("v77","v80","v25","13") FM("v78","v80","v26","14") FM("v79","v80","v27","15")
// DPP quarter B: 16 cols at probed base gB (weights v28-43)
#define QB \
 FM("v76","v81","v28","0")  FM("v77","v81","v29","1")  FM("v78","v81","v30","2")  FM("v79","v81","v31","3") \
 FM("v76","v81","v32","4")  FM("v77","v81","v33","5")  FM("v78","v81","v34","6")  FM("v79","v81","v35","7") \
 FM("v76","v81","v36","8")  FM("v77","v81","v37","9")  FM("v78","v81","v38","10") FM("v79","v81","v39","11") \
 FM("v76","v81","v40","12") FM("v77","v81","v41","13") FM("v78","v81","v42","14") FM("v79","v81","v43","15")

#define RD8 \
 "ds_read_b128 v[128:131], v88\n\t" \
 "ds_read_b128 v[132:135], v88 offset:16\n\t" \
 "ds_read_b128 v[136:139], v88 offset:32\n\t" \
 "ds_read_b128 v[140:143], v88 offset:48\n\t" \
 "ds_read_b128 v[144:147], v88 offset:64\n\t" \
 "ds_read_b128 v[148:151], v88 offset:80\n\t" \
 "ds_read_b128 v[152:155], v88 offset:96\n\t" \
 "ds_read_b128 v[156:159], v88 offset:112\n\t"

// pk chains p0=v[104:105] (seeded by x pair v[92:93], v93=0), p1=v[106:107].
#define PK_A \
 "v_pk_fma_f32 v[104:105], v[128:129], v[44:45], v[92:93]\n\t" \
 "v_pk_mul_f32 v[106:107], v[130:131], v[46:47]\n\t" \
 "v_pk_fma_f32 v[104:105], v[132:133], v[48:49], v[104:105]\n\t" \
 "v_pk_fma_f32 v[106:107], v[134:135], v[50:51], v[106:107]\n\t" \
 "v_pk_fma_f32 v[104:105], v[136:137], v[52:53], v[104:105]\n\t" \
 "v_pk_fma_f32 v[106:107], v[138:139], v[54:55], v[106:107]\n\t" \
 "v_pk_fma_f32 v[104:105], v[140:141], v[56:57], v[104:105]\n\t" \
 "v_pk_fma_f32 v[106:107], v[142:143], v[58:59], v[106:107]\n\t"
#define PK_B \
 "v_pk_fma_f32 v[104:105], v[144:145], v[60:61], v[104:105]\n\t" \
 "v_pk_fma_f32 v[106:107], v[146:147], v[62:63], v[106:107]\n\t" \
 "v_pk_fma_f32 v[104:105], v[148:149], v[64:65], v[104:105]\n\t" \
 "v_pk_fma_f32 v[106:107], v[150:151], v[66:67], v[106:107]\n\t" \
 "v_pk_fma_f32 v[104:105], v[152:153], v[68:69], v[104:105]\n\t" \
 "v_pk_fma_f32 v[106:107], v[154:155], v[70:71], v[106:107]\n\t" \
 "v_pk_fma_f32 v[104:105], v[156:157], v[72:73], v[104:105]\n\t" \
 "v_pk_fma_f32 v[106:107], v[158:159], v[74:75], v[106:107]\n\t"

// combine pk + dpp chains, relu into v84 (persistent) and v80,v81 (tree).
#define TAIL \
 "v_pk_add_f32 v[104:105], v[104:105], v[106:107]\n\t" \
 "v_add_f32 v104, v104, v105\n\t" \
 "v_add_f32 v76, v76, v77\n\t" \
 "v_add_f32 v78, v78, v79\n\t" \
 "v_add_f32 v76, v76, v78\n\t" \
 "v_add_f32 v76, v76, v104\n\t" \
 "v_max_f32 v84, 0, v76\n\t" \
 "v_max_f32 v80, 0, v76\n\t" \
 "v_max_f32 v81, 0, v76\n\t"

// Body: publish h, issue the 8 half reads, swap tree, x-seed during the DS
// window, 32 DPP fmacs (fill), staged lgkm waits, 16 pk, tail.
// DS ops/body = 9 (write + 8 reads):
//   lgkmcnt(4): write + reads 0-3 done -> PK_A (v128-143)
//   lgkmcnt(0): all done              -> PK_B (v144-159)
#define BODY(XL, XH, BUMP, LOADX) \
 "ds_write_b32 v86, v84\n\t" \
 RD8 \
 "v_permlane16_swap_b32 v80, v81\n\t" \
 "s_waitcnt vmcnt(1)\n\t" \
 "v_mul_f32 v92, " XL ", v90\n\t" \
 "v_fmac_f32 v92, " XH ", v91\n\t" \
 BUMP \
 LOADX \
 QA \
 QB \
 "s_waitcnt lgkmcnt(4)\n\t" \
 PK_A \
 "s_waitcnt lgkmcnt(0)\n\t" \
 PK_B \
 TAIL

#define BUMP_EVEN \
 "v_add_u32 v100, 16, v100\n\t" \
 "v_min_u32 v100, 0x3ff0, v100\n\t"
#define LOAD_EVEN "global_load_dwordx2 v[96:97], v100, %[xb]\n\t"
#define LOAD_ODD  "global_load_dwordx2 v[98:99], v100, %[xb] offset:8\n\t"

__global__ __launch_bounds__(64, 1) void rnn_scan_kernel(
    const float* __restrict__ x,    // [B, T, 2]
    const float* __restrict__ Wh,   // [64, 64] row-major
    const float* __restrict__ Wx,   // [64, 2]
    float* __restrict__ out)        // [B]
{
    extern __shared__ float lds[];  // 64 floats (bytes 0..255)

    const int b = blockIdx.x;
    const int j = threadIdx.x;   // 0..63, lane == hidden/output index

    const float* xb = x + (size_t)b * TT * II;

    float h;
    asm volatile(
        // ---- PROBE: which h-group do v80/v81 broadcast for MY row? ---------
        // Fill with lane index; after p16-swap, lane l's own slot value is
        // 16*gA(row(l)) + (l&15)  ->  gA = value>>4 (same for v81 -> gB).
        "v_mov_b32 v80, %[lane]\n\t"
        "v_mov_b32 v81, %[lane]\n\t"
        "s_nop 7\n\t"
        "v_permlane16_swap_b32 v80, v81\n\t"
        "s_nop 7\n\t"
        "v_lshrrev_b32 v102, 4, v80\n\t"
        "v_lshlrev_b32 v102, 6, v102\n\t"          // gA byte offset (col base*4)
        "v_lshrrev_b32 v103, 4, v81\n\t"
        "v_lshlrev_b32 v103, 6, v103\n\t"          // gB byte offset
        "v_lshlrev_b32 v101, 8, %[lane]\n\t"       // j*256 (W row byte base)
        "v_add_u32 v102, v101, v102\n\t"
        "v_add_u32 v103, v101, v103\n\t"
        // ---- DPP weight banks: A (v12-27), B (v28-43) ----------------------
        "global_load_dwordx4 v[12:15], v102, %[wh]\n\t"
        "global_load_dwordx4 v[16:19], v102, %[wh] offset:16\n\t"
        "global_load_dwordx4 v[20:23], v102, %[wh] offset:32\n\t"
        "global_load_dwordx4 v[24:27], v102, %[wh] offset:48\n\t"
        "global_load_dwordx4 v[28:31], v103, %[wh]\n\t"
        "global_load_dwordx4 v[32:35], v103, %[wh] offset:16\n\t"
        "global_load_dwordx4 v[36:39], v103, %[wh] offset:32\n\t"
        "global_load_dwordx4 v[40:43], v103, %[wh] offset:48\n\t"
        // ---- pk half: base = opposite 32 cols of my row's half -------------
        // rows 0,1 (l<32) -> bytes 128..255 ; rows 2,3 -> bytes 0..127
        "v_lshrrev_b32 v88, 5, %[lane]\n\t"
        "v_xor_b32 v88, 1, v88\n\t"
        "v_lshlrev_b32 v88, 7, v88\n\t"            // LDS read base (halfbase)
        "v_add_u32 v103, v101, v88\n\t"            // pk W addr
        "global_load_dwordx4 v[44:47], v103, %[wh]\n\t"
        "global_load_dwordx4 v[48:51], v103, %[wh] offset:16\n\t"
        "global_load_dwordx4 v[52:55], v103, %[wh] offset:32\n\t"
        "global_load_dwordx4 v[56:59], v103, %[wh] offset:48\n\t"
        "global_load_dwordx4 v[60:63], v103, %[wh] offset:64\n\t"
        "global_load_dwordx4 v[64:67], v103, %[wh] offset:80\n\t"
        "global_load_dwordx4 v[68:71], v103, %[wh] offset:96\n\t"
        "global_load_dwordx4 v[72:75], v103, %[wh] offset:112\n\t"
        // wx row j -> v90:91
        "v_lshlrev_b32 v102, 3, %[lane]\n\t"
        "global_load_dwordx2 v[90:91], v102, %[wx]\n\t"
        // x prefetch: even pair = x(t=0), odd pair = x(t=1)
        "v_mov_b32 v100, 0\n\t"
        "global_load_dwordx2 v[96:97], v100, %[xb]\n\t"
        "global_load_dwordx2 v[98:99], v100, %[xb] offset:8\n\t"
        // LDS write addr = lane*4; h/tree init; seed hi = 0
        "v_lshlrev_b32 v86, 2, %[lane]\n\t"
        "v_mov_b32 v84, 0\n\t"
        "v_mov_b32 v80, 0\n\t"
        "v_mov_b32 v81, 0\n\t"
        "v_mov_b32 v93, 0\n\t"
        "s_movk_i32 s16, 0x400\n\t"
        "s_waitcnt vmcnt(2)\n\t"                    // weights+wx done; 2 x in flight
        // ---- main loop: 1024 x (even body + odd body) = 2048 steps ---------
        "LTOP_%=:\n\t"
        BODY("v96", "v97", BUMP_EVEN, LOAD_EVEN)
        BODY("v98", "v99", , LOAD_ODD)
        "s_sub_u32 s16, s16, 1\n\t"
        "s_cmp_lg_u32 s16, 0\n\t"
        "s_cbranch_scc1 LTOP_%=\n\t"
        // ---- epilogue ------------------------------------------------------
        "s_waitcnt vmcnt(0) lgkmcnt(0)\n\t"
        "v_mov_b32 %[h], v84\n\t"
        : [h] "=&v"(h)
        : [lane] "v"(j), [wh] "s"(Wh), [xb] "s"(xb), [wx] "s"(Wx)
        : "memory", "scc",
          "v12","v13","v14","v15","v16","v17","v18","v19",
          "v20","v21","v22","v23","v24","v25","v26","v27",
          "v28","v29","v30","v31","v32","v33","v34","v35",
          "v36","v37","v38","v39","v40","v41","v42","v43",
          "v44","v45","v46","v47","v48","v49","v50","v51",
          "v52","v53","v54","v55","v56","v57","v58","v59",
          "v60","v61","v62","v63","v64","v65","v66","v67",
          "v68","v69","v70","v71","v72","v73","v74","v75",
          "v76","v77","v78","v79","v80","v81","v84","v86","v88",
          "v90","v91","v92","v93","v96","v97","v98","v99",
          "v100","v101","v102","v103","v104","v105","v106","v107",
          "v128","v129","v130","v131","v132","v133","v134","v135",
          "v136","v137","v138","v139","v140","v141","v142","v143",
          "v144","v145","v146","v147","v148","v149","v150","v151",
          "v152","v153","v154","v155","v156","v157","v158","v159",
          "s16");

    // ||h_T||_2 across the wave (v84 = h[j] at lane j)
    float s = h * h;
#pragma unroll
    for (int off = 32; off > 0; off >>= 1)
        s += __shfl_xor(s, off, 64);
    if (j == 0)
        out[b] = sqrtf(s);
}

extern "C" void kernel_launch(void* const* d_in, const int* in_sizes, int n_in,
                              void* d_out, int out_size, void* d_ws, size_t ws_size,
                              hipStream_t stream) {
    const float* x  = (const float*)d_in[0];   // [B,T,2]
    const float* Wh = (const float*)d_in[1];   // [64,64]
    const float* Wx = (const float*)d_in[2];   // [64,2]
    float* out = (float*)d_out;                // [B]

    rnn_scan_kernel<<<dim3(BB), dim3(64), 256, stream>>>(x, Wh, Wx, out);
}

// Round 15
// 315.421 us; speedup vs baseline: 1.0606x; 1.0606x over previous
//
#include <hip/hip_runtime.h>
#include <math.h>

// Problem constants (match reference)
#define BB 1024
#define TT 2048
#define II 2
#define HH 64

// ---- Balanced DPP + packed-f32 hybrid --------------------------------------
// Per step, 64 cols split at the issue/DS balance point:
//  * 16 cols [16g,16g+16): DPP row_newbcast directly on v84 (h) -- lane l in
//    row-group g gets h[16g+r] at bcast r; weights W[l][16g+r] in v12-27
//    (r5-proven pattern). No swap tree, no probe. These 16 fmacs fill the
//    LDS write->read latency window.
//  * 48-col complement (16(g+1)+c mod 64, c=0..47): h written DOUBLED to LDS
//    (bytes 0..255 and 256..511), so each group's complement is contiguous at
//    base 64(g+1). 12 ds_read_b128 at the group base (4 distinct addrs, 2-way
//    bank aliasing = free) + 24 v_pk_fma_f32 (2 exact f32 MACs each).
//    pk weight banks loaded ROTATED per lane: chunk i from
//    rowbase + ((64(g+1)+16i) & 255)  (16B chunks never wrap internally).
#define FM(a,w,r) "v_fmac_f32 " a ", v84, " w " row_newbcast:" r "\n\t"
#define MU(a,w,r) "v_mul_f32 "  a ", v84, " w " row_newbcast:" r "\n\t"

#define Q0 \
 MU("v78","v12","0")  MU("v79","v13","1")  FM("v78","v14","2")  FM("v79","v15","3") \
 FM("v78","v16","4")  FM("v79","v17","5")  FM("v78","v18","6")  FM("v79","v19","7") \
 FM("v78","v20","8")  FM("v79","v21","9")  FM("v78","v22","10") FM("v79","v23","11") \
 FM("v78","v24","12") FM("v79","v25","13") FM("v78","v26","14") FM("v79","v27","15")

#define RD12 \
 "ds_read_b128 v[128:131], v88\n\t" \
 "ds_read_b128 v[132:135], v88 offset:16\n\t" \
 "ds_read_b128 v[136:139], v88 offset:32\n\t" \
 "ds_read_b128 v[140:143], v88 offset:48\n\t" \
 "ds_read_b128 v[144:147], v88 offset:64\n\t" \
 "ds_read_b128 v[148:151], v88 offset:80\n\t" \
 "ds_read_b128 v[152:155], v88 offset:96\n\t" \
 "ds_read_b128 v[156:159], v88 offset:112\n\t" \
 "ds_read_b128 v[160:163], v88 offset:128\n\t" \
 "ds_read_b128 v[164:167], v88 offset:144\n\t" \
 "ds_read_b128 v[168:171], v88 offset:160\n\t" \
 "ds_read_b128 v[172:175], v88 offset:176\n\t"

// 4 pk chains v104-111; chain0 seeded by the x pair v[92:93] (v93 == 0).
#define PK_0_7 \
 "v_pk_fma_f32 v[104:105], v[128:129], v[28:29], v[92:93]\n\t" \
 "v_pk_mul_f32 v[106:107], v[130:131], v[30:31]\n\t" \
 "v_pk_mul_f32 v[108:109], v[132:133], v[32:33]\n\t" \
 "v_pk_mul_f32 v[110:111], v[134:135], v[34:35]\n\t" \
 "v_pk_fma_f32 v[104:105], v[136:137], v[36:37], v[104:105]\n\t" \
 "v_pk_fma_f32 v[106:107], v[138:139], v[38:39], v[106:107]\n\t" \
 "v_pk_fma_f32 v[108:109], v[140:141], v[40:41], v[108:109]\n\t" \
 "v_pk_fma_f32 v[110:111], v[142:143], v[42:43], v[110:111]\n\t"
#define PK_8_15 \
 "v_pk_fma_f32 v[104:105], v[144:145], v[44:45], v[104:105]\n\t" \
 "v_pk_fma_f32 v[106:107], v[146:147], v[46:47], v[106:107]\n\t" \
 "v_pk_fma_f32 v[108:109], v[148:149], v[48:49], v[108:109]\n\t" \
 "v_pk_fma_f32 v[110:111], v[150:151], v[50:51], v[110:111]\n\t" \
 "v_pk_fma_f32 v[104:105], v[152:153], v[52:53], v[104:105]\n\t" \
 "v_pk_fma_f32 v[106:107], v[154:155], v[54:55], v[106:107]\n\t" \
 "v_pk_fma_f32 v[108:109], v[156:157], v[56:57], v[108:109]\n\t" \
 "v_pk_fma_f32 v[110:111], v[158:159], v[58:59], v[110:111]\n\t"
#define PK_16_23 \
 "v_pk_fma_f32 v[104:105], v[160:161], v[60:61], v[104:105]\n\t" \
 "v_pk_fma_f32 v[106:107], v[162:163], v[62:63], v[106:107]\n\t" \
 "v_pk_fma_f32 v[108:109], v[164:165], v[64:65], v[108:109]\n\t" \
 "v_pk_fma_f32 v[110:111], v[166:167], v[66:67], v[110:111]\n\t" \
 "v_pk_fma_f32 v[104:105], v[168:169], v[68:69], v[104:105]\n\t" \
 "v_pk_fma_f32 v[106:107], v[170:171], v[70:71], v[106:107]\n\t" \
 "v_pk_fma_f32 v[108:109], v[172:173], v[72:73], v[108:109]\n\t" \
 "v_pk_fma_f32 v[110:111], v[174:175], v[74:75], v[110:111]\n\t"

// combine pk chains + DPP chains, relu -> v84
#define TAIL \
 "v_pk_add_f32 v[104:105], v[104:105], v[106:107]\n\t" \
 "v_pk_add_f32 v[108:109], v[108:109], v[110:111]\n\t" \
 "v_pk_add_f32 v[104:105], v[104:105], v[108:109]\n\t" \
 "v_add_f32 v104, v104, v105\n\t" \
 "v_add_f32 v78, v78, v79\n\t" \
 "v_add_f32 v104, v104, v78\n\t" \
 "v_max_f32 v84, 0, v104\n\t"

// Body: publish h (doubled), 12 complement reads, x-seed + Q0 as latency
// filler, staged lgkm waits (14 DS ops: 2W+12R):
//   lgkmcnt(8): 2W + r0-3 done  -> PK_0_7   (v128-143)
//   lgkmcnt(4): r4-7 done       -> PK_8_15  (v144-159)
//   lgkmcnt(0): all done        -> PK_16_23 (v160-175)
#define BODY(XL, XH, BUMP, LOADX) \
 "ds_write_b32 v86, v84\n\t" \
 "ds_write_b32 v86, v84 offset:256\n\t" \
 RD12 \
 "s_waitcnt vmcnt(1)\n\t" \
 "v_mul_f32 v92, " XL ", v90\n\t" \
 "v_fmac_f32 v92, " XH ", v91\n\t" \
 BUMP \
 LOADX \
 Q0 \
 "s_waitcnt lgkmcnt(8)\n\t" \
 PK_0_7 \
 "s_waitcnt lgkmcnt(4)\n\t" \
 PK_8_15 \
 "s_waitcnt lgkmcnt(0)\n\t" \
 PK_16_23 \
 TAIL

#define BUMP_EVEN \
 "v_add_u32 v100, 16, v100\n\t" \
 "v_min_u32 v100, 0x3ff0, v100\n\t"
#define LOAD_EVEN "global_load_dwordx2 v[96:97], v100, %[xb]\n\t"
#define LOAD_ODD  "global_load_dwordx2 v[98:99], v100, %[xb] offset:8\n\t"

// pk weight chunk load i: addr = rowbase + ((64*(g+1) + 16*i) & 255)
#define PKW(i, d0, d3) \
 "v_add_u32 v106, " #i ", v88\n\t" \
 "v_and_b32 v106, 0xff, v106\n\t" \
 "v_add_u32 v106, v101, v106\n\t" \
 "global_load_dwordx4 v[" #d0 ":" #d3 "], v106, %[wh]\n\t"

__global__ __launch_bounds__(64, 1) void rnn_scan_kernel(
    const float* __restrict__ x,    // [B, T, 2]
    const float* __restrict__ Wh,   // [64, 64] row-major
    const float* __restrict__ Wx,   // [64, 2]
    float* __restrict__ out)        // [B]
{
    extern __shared__ float lds[];  // 128 floats: h doubled (bytes 0..511)

    const int b = blockIdx.x;
    const int j = threadIdx.x;   // 0..63, lane == hidden/output index

    const float* xb = x + (size_t)b * TT * II;

    float h;
    asm volatile(
        // ---- prologue ------------------------------------------------------
        "v_lshlrev_b32 v101, 8, %[lane]\n\t"       // rowbase = j*256
        "v_lshrrev_b32 v102, 4, %[lane]\n\t"       // g
        "v_lshlrev_b32 v103, 6, v102\n\t"          // g*64
        // Q0 bank: W[j][16g + 0..15] -> v12..v27
        "v_add_u32 v104, v101, v103\n\t"
        "global_load_dwordx4 v[12:15], v104, %[wh]\n\t"
        "global_load_dwordx4 v[16:19], v104, %[wh] offset:16\n\t"
        "global_load_dwordx4 v[20:23], v104, %[wh] offset:32\n\t"
        "global_load_dwordx4 v[24:27], v104, %[wh] offset:48\n\t"
        // rotation/read base = 64*(g+1)  (also the LDS read base)
        "v_add_u32 v88, 64, v103\n\t"
        // pk banks: rotated row -> v28..v75 (12 chunks, mod-256 wrap)
        PKW(0,   28, 31)
        PKW(16,  32, 35)
        PKW(32,  36, 39)
        PKW(48,  40, 43)
        PKW(64,  44, 47)
        PKW(80,  48, 51)
        PKW(96,  52, 55)
        PKW(112, 56, 59)
        PKW(128, 60, 63)
        PKW(144, 64, 67)
        PKW(160, 68, 71)
        PKW(176, 72, 75)
        // wx row j -> v90:91
        "v_lshlrev_b32 v105, 3, %[lane]\n\t"
        "global_load_dwordx2 v[90:91], v105, %[wx]\n\t"
        // x prefetch: even pair = x(t=0), odd pair = x(t=1)
        "v_mov_b32 v100, 0\n\t"
        "global_load_dwordx2 v[96:97], v100, %[xb]\n\t"
        "global_load_dwordx2 v[98:99], v100, %[xb] offset:8\n\t"
        // LDS write addr = lane*4 (doubled via offset:256)
        "v_lshlrev_b32 v86, 2, %[lane]\n\t"
        // h_{-1} = 0; seed hi = 0; loop counter
        "v_mov_b32 v84, 0\n\t"
        "v_mov_b32 v93, 0\n\t"
        "s_movk_i32 s16, 0x400\n\t"
        "s_waitcnt vmcnt(2)\n\t"                    // weights+wx done; 2 x in flight
        // ---- main loop: 1024 x (even body + odd body) = 2048 steps ---------
        "LTOP_%=:\n\t"
        BODY("v96", "v97", BUMP_EVEN, LOAD_EVEN)
        BODY("v98", "v99", , LOAD_ODD)
        "s_sub_u32 s16, s16, 1\n\t"
        "s_cmp_lg_u32 s16, 0\n\t"
        "s_cbranch_scc1 LTOP_%=\n\t"
        // ---- epilogue ------------------------------------------------------
        "s_waitcnt vmcnt(0) lgkmcnt(0)\n\t"
        "v_mov_b32 %[h], v84\n\t"
        : [h] "=&v"(h)
        : [lane] "v"(j), [wh] "s"(Wh), [xb] "s"(xb), [wx] "s"(Wx)
        : "memory", "scc",
          "v12","v13","v14","v15","v16","v17","v18","v19",
          "v20","v21","v22","v23","v24","v25","v26","v27",
          "v28","v29","v30","v31","v32","v33","v34","v35",
          "v36","v37","v38","v39","v40","v41","v42","v43",
          "v44","v45","v46","v47","v48","v49","v50","v51",
          "v52","v53","v54","v55","v56","v57","v58","v59",
          "v60","v61","v62","v63","v64","v65","v66","v67",
          "v68","v69","v70","v71","v72","v73","v74","v75",
          "v78","v79","v84","v86","v88",
          "v90","v91","v92","v93","v96","v97","v98","v99",
          "v100","v101","v102","v103","v104","v105","v106","v107",
          "v108","v109","v110","v111",
          "v128","v129","v130","v131","v132","v133","v134","v135",
          "v136","v137","v138","v139","v140","v141","v142","v143",
          "v144","v145","v146","v147","v148","v149","v150","v151",
          "v152","v153","v154","v155","v156","v157","v158","v159",
          "v160","v161","v162","v163","v164","v165","v166","v167",
          "v168","v169","v170","v171","v172","v173","v174","v175",
          "s16");

    // ||h_T||_2 across the wave (v84 = h[j] at lane j)
    float s = h * h;
#pragma unroll
    for (int off = 32; off > 0; off >>= 1)
        s += __shfl_xor(s, off, 64);
    if (j == 0)
        out[b] = sqrtf(s);
}

extern "C" void kernel_launch(void* const* d_in, const int* in_sizes, int n_in,
                              void* d_out, int out_size, void* d_ws, size_t ws_size,
                              hipStream_t stream) {
    const float* x  = (const float*)d_in[0];   // [B,T,2]
    const float* Wh = (const float*)d_in[1];   // [64,64]
    const float* Wx = (const float*)d_in[2];   // [64,2]
    float* out = (float*)d_out;                // [B]

    rnn_scan_kernel<<<dim3(BB), dim3(64), 512, stream>>>(x, Wh, Wx, out);
}

// Round 16
// 310.694 us; speedup vs baseline: 1.0767x; 1.0152x over previous
//
#include <hip/hip_runtime.h>
#include <math.h>

// Problem constants (match reference)
#define BB 1024
#define TT 2048
#define II 2
#define HH 64

// ---- Balanced DPP + packed-f32 hybrid, conflict-free reads ------------------
// Per step, 64 cols split:
//  * 16 cols [16g,16g+16): DPP row_newbcast directly on v84 (r5/r15-proven).
//  * 48-col complement as 12 quads q(g,i) = (4(g+1)+i) & 15, i=0..11:
//    h written ONCE to LDS (256 B), read i at per-lane address
//    a_i = (64(g+1)+16i) & 255 (precomputed in v112+i). Across the 4 groups,
//    read i hits 2 banks x 2 addresses = 2-way aliasing = free (m136).
//    24 v_pk_fma_f32 cover the 48 cols; weight chunk i loaded in the
//    prologue from rowbase + a_i (matches quad q(g,i)).
// Model: issue ~69 instrs x 4 cyc (solo-wave cadence) = 276; DS pipe
// 13 ops x ~5.2 cyc x 4 waves/CU = 270 -> balanced at ~310 cyc/step.
#define FM(a,w,r) "v_fmac_f32 " a ", v84, " w " row_newbcast:" r "\n\t"
#define MU(a,w,r) "v_mul_f32 "  a ", v84, " w " row_newbcast:" r "\n\t"

#define Q0 \
 MU("v78","v12","0")  MU("v79","v13","1")  FM("v78","v14","2")  FM("v79","v15","3") \
 FM("v78","v16","4")  FM("v79","v17","5")  FM("v78","v18","6")  FM("v79","v19","7") \
 FM("v78","v20","8")  FM("v79","v21","9")  FM("v78","v22","10") FM("v79","v23","11") \
 FM("v78","v24","12") FM("v79","v25","13") FM("v78","v26","14") FM("v79","v27","15")

// 12 reads at precomputed wrapped addresses (v112..v123)
#define RD12 \
 "ds_read_b128 v[128:131], v112\n\t" \
 "ds_read_b128 v[132:135], v113\n\t" \
 "ds_read_b128 v[136:139], v114\n\t" \
 "ds_read_b128 v[140:143], v115\n\t" \
 "ds_read_b128 v[144:147], v116\n\t" \
 "ds_read_b128 v[148:151], v117\n\t" \
 "ds_read_b128 v[152:155], v118\n\t" \
 "ds_read_b128 v[156:159], v119\n\t" \
 "ds_read_b128 v[160:163], v120\n\t" \
 "ds_read_b128 v[164:167], v121\n\t" \
 "ds_read_b128 v[168:171], v122\n\t" \
 "ds_read_b128 v[172:175], v123\n\t"

// 4 pk chains v104-111; chain0 seeded by the x pair v[92:93] (v93 == 0).
#define PK_0_7 \
 "v_pk_fma_f32 v[104:105], v[128:129], v[28:29], v[92:93]\n\t" \
 "v_pk_mul_f32 v[106:107], v[130:131], v[30:31]\n\t" \
 "v_pk_mul_f32 v[108:109], v[132:133], v[32:33]\n\t" \
 "v_pk_mul_f32 v[110:111], v[134:135], v[34:35]\n\t" \
 "v_pk_fma_f32 v[104:105], v[136:137], v[36:37], v[104:105]\n\t" \
 "v_pk_fma_f32 v[106:107], v[138:139], v[38:39], v[106:107]\n\t" \
 "v_pk_fma_f32 v[108:109], v[140:141], v[40:41], v[108:109]\n\t" \
 "v_pk_fma_f32 v[110:111], v[142:143], v[42:43], v[110:111]\n\t"
#define PK_8_15 \
 "v_pk_fma_f32 v[104:105], v[144:145], v[44:45], v[104:105]\n\t" \
 "v_pk_fma_f32 v[106:107], v[146:147], v[46:47], v[106:107]\n\t" \
 "v_pk_fma_f32 v[108:109], v[148:149], v[48:49], v[108:109]\n\t" \
 "v_pk_fma_f32 v[110:111], v[150:151], v[50:51], v[110:111]\n\t" \
 "v_pk_fma_f32 v[104:105], v[152:153], v[52:53], v[104:105]\n\t" \
 "v_pk_fma_f32 v[106:107], v[154:155], v[54:55], v[106:107]\n\t" \
 "v_pk_fma_f32 v[108:109], v[156:157], v[56:57], v[108:109]\n\t" \
 "v_pk_fma_f32 v[110:111], v[158:159], v[58:59], v[110:111]\n\t"
#define PK_16_23 \
 "v_pk_fma_f32 v[104:105], v[160:161], v[60:61], v[104:105]\n\t" \
 "v_pk_fma_f32 v[106:107], v[162:163], v[62:63], v[106:107]\n\t" \
 "v_pk_fma_f32 v[108:109], v[164:165], v[64:65], v[108:109]\n\t" \
 "v_pk_fma_f32 v[110:111], v[166:167], v[66:67], v[110:111]\n\t" \
 "v_pk_fma_f32 v[104:105], v[168:169], v[68:69], v[104:105]\n\t" \
 "v_pk_fma_f32 v[106:107], v[170:171], v[70:71], v[106:107]\n\t" \
 "v_pk_fma_f32 v[108:109], v[172:173], v[72:73], v[108:109]\n\t" \
 "v_pk_fma_f32 v[110:111], v[174:175], v[74:75], v[110:111]\n\t"

// combine pk chains + DPP chains, relu -> v84
#define TAIL \
 "v_pk_add_f32 v[104:105], v[104:105], v[106:107]\n\t" \
 "v_pk_add_f32 v[108:109], v[108:109], v[110:111]\n\t" \
 "v_pk_add_f32 v[104:105], v[104:105], v[108:109]\n\t" \
 "v_add_f32 v104, v104, v105\n\t" \
 "v_add_f32 v78, v78, v79\n\t" \
 "v_add_f32 v104, v104, v78\n\t" \
 "v_max_f32 v84, 0, v104\n\t"

// Body. 13 DS ops (1W + 12R), staged:
//   lgkmcnt(8): W + r0-3 done -> PK_0_7   (v128-143)
//   lgkmcnt(4): r4-7 done     -> PK_8_15  (v144-159)
//   lgkmcnt(0): all done      -> PK_16_23 (v160-175)
#define BODY(XL, XH, BUMP, LOADX) \
 "ds_write_b32 v86, v84\n\t" \
 RD12 \
 "s_waitcnt vmcnt(1)\n\t" \
 "v_mul_f32 v92, " XL ", v90\n\t" \
 "v_fmac_f32 v92, " XH ", v91\n\t" \
 BUMP \
 LOADX \
 Q0 \
 "s_waitcnt lgkmcnt(8)\n\t" \
 PK_0_7 \
 "s_waitcnt lgkmcnt(4)\n\t" \
 PK_8_15 \
 "s_waitcnt lgkmcnt(0)\n\t" \
 PK_16_23 \
 TAIL

#define BUMP_EVEN \
 "v_add_u32 v100, 16, v100\n\t" \
 "v_min_u32 v100, 0x3ff0, v100\n\t"
#define LOAD_EVEN "global_load_dwordx2 v[96:97], v100, %[xb]\n\t"
#define LOAD_ODD  "global_load_dwordx2 v[98:99], v100, %[xb] offset:8\n\t"

// read addr i: a_i = (64*(g+1) + 16*i) & 255  (v88 = 64*(g+1))
#define MKADDR(i, dst) \
 "v_add_u32 " dst ", " #i ", v88\n\t" \
 "v_and_b32 " dst ", 0xff, " dst "\n\t"

// pk weight chunk i from rowbase + a_i
#define PKW(ai, d0, d3) \
 "v_add_u32 v106, v101, " ai "\n\t" \
 "global_load_dwordx4 v[" #d0 ":" #d3 "], v106, %[wh]\n\t"

__global__ __launch_bounds__(64, 1) void rnn_scan_kernel(
    const float* __restrict__ x,    // [B, T, 2]
    const float* __restrict__ Wh,   // [64, 64] row-major
    const float* __restrict__ Wx,   // [64, 2]
    float* __restrict__ out)        // [B]
{
    extern __shared__ float lds[];  // 64 floats (bytes 0..255)

    const int b = blockIdx.x;
    const int j = threadIdx.x;   // 0..63, lane == hidden/output index

    const float* xb = x + (size_t)b * TT * II;

    float h;
    asm volatile(
        // ---- prologue ------------------------------------------------------
        "v_lshlrev_b32 v101, 8, %[lane]\n\t"       // rowbase = j*256
        "v_lshrrev_b32 v102, 4, %[lane]\n\t"       // g
        "v_lshlrev_b32 v103, 6, v102\n\t"          // g*64
        // Q0 bank: W[j][16g + 0..15] -> v12..v27
        "v_add_u32 v104, v101, v103\n\t"
        "global_load_dwordx4 v[12:15], v104, %[wh]\n\t"
        "global_load_dwordx4 v[16:19], v104, %[wh] offset:16\n\t"
        "global_load_dwordx4 v[20:23], v104, %[wh] offset:32\n\t"
        "global_load_dwordx4 v[24:27], v104, %[wh] offset:48\n\t"
        // v88 = 64*(g+1); wrapped read addrs a_0..a_11 -> v112..v123
        "v_add_u32 v88, 64, v103\n\t"
        MKADDR(0,   "v112")
        MKADDR(16,  "v113")
        MKADDR(32,  "v114")
        MKADDR(48,  "v115")
        MKADDR(64,  "v116")
        MKADDR(80,  "v117")
        MKADDR(96,  "v118")
        MKADDR(112, "v119")
        MKADDR(128, "v120")
        MKADDR(144, "v121")
        MKADDR(160, "v122")
        MKADDR(176, "v123")
        // pk banks: chunk i from rowbase + a_i -> v28..v75
        PKW("v112", 28, 31)
        PKW("v113", 32, 35)
        PKW("v114", 36, 39)
        PKW("v115", 40, 43)
        PKW("v116", 44, 47)
        PKW("v117", 48, 51)
        PKW("v118", 52, 55)
        PKW("v119", 56, 59)
        PKW("v120", 60, 63)
        PKW("v121", 64, 67)
        PKW("v122", 68, 71)
        PKW("v123", 72, 75)
        // wx row j -> v90:91
        "v_lshlrev_b32 v105, 3, %[lane]\n\t"
        "global_load_dwordx2 v[90:91], v105, %[wx]\n\t"
        // x prefetch: even pair = x(t=0), odd pair = x(t=1)
        "v_mov_b32 v100, 0\n\t"
        "global_load_dwordx2 v[96:97], v100, %[xb]\n\t"
        "global_load_dwordx2 v[98:99], v100, %[xb] offset:8\n\t"
        // LDS write addr = lane*4
        "v_lshlrev_b32 v86, 2, %[lane]\n\t"
        // h_{-1} = 0; seed hi = 0; loop counter
        "v_mov_b32 v84, 0\n\t"
        "v_mov_b32 v93, 0\n\t"
        "s_movk_i32 s16, 0x400\n\t"
        "s_waitcnt vmcnt(2)\n\t"                    // weights+wx done; 2 x in flight
        // ---- main loop: 1024 x (even body + odd body) = 2048 steps ---------
        "LTOP_%=:\n\t"
        BODY("v96", "v97", BUMP_EVEN, LOAD_EVEN)
        BODY("v98", "v99", , LOAD_ODD)
        "s_sub_u32 s16, s16, 1\n\t"
        "s_cmp_lg_u32 s16, 0\n\t"
        "s_cbranch_scc1 LTOP_%=\n\t"
        // ---- epilogue ------------------------------------------------------
        "s_waitcnt vmcnt(0) lgkmcnt(0)\n\t"
        "v_mov_b32 %[h], v84\n\t"
        : [h] "=&v"(h)
        : [lane] "v"(j), [wh] "s"(Wh), [xb] "s"(xb), [wx] "s"(Wx)
        : "memory", "scc",
          "v12","v13","v14","v15","v16","v17","v18","v19",
          "v20","v21","v22","v23","v24","v25","v26","v27",
          "v28","v29","v30","v31","v32","v33","v34","v35",
          "v36","v37","v38","v39","v40","v41","v42","v43",
          "v44","v45","v46","v47","v48","v49","v50","v51",
          "v52","v53","v54","v55","v56","v57","v58","v59",
          "v60","v61","v62","v63","v64","v65","v66","v67",
          "v68","v69","v70","v71","v72","v73","v74","v75",
          "v78","v79","v84","v86","v88",
          "v90","v91","v92","v93","v96","v97","v98","v99",
          "v100","v101","v102","v103","v104","v105","v106","v107",
          "v108","v109","v110","v111",
          "v112","v113","v114","v115","v116","v117","v118","v119",
          "v120","v121","v122","v123",
          "v128","v129","v130","v131","v132","v133","v134","v135",
          "v136","v137","v138","v139","v140","v141","v142","v143",
          "v144","v145","v146","v147","v148","v149","v150","v151",
          "v152","v153","v154","v155","v156","v157","v158","v159",
          "v160","v161","v162","v163","v164","v165","v166","v167",
          "v168","v169","v170","v171","v172","v173","v174","v175",
          "s16");

    // ||h_T||_2 across the wave (v84 = h[j] at lane j)
    float s = h * h;
#pragma unroll
    for (int off = 32; off > 0; off >>= 1)
        s += __shfl_xor(s, off, 64);
    if (j == 0)
        out[b] = sqrtf(s);
}

extern "C" void kernel_launch(void* const* d_in, const int* in_sizes, int n_in,
                              void* d_out, int out_size, void* d_ws, size_t ws_size,
                              hipStream_t stream) {
    const float* x  = (const float*)d_in[0];   // [B,T,2]
    const float* Wh = (const float*)d_in[1];   // [64,64]
    const float* Wx = (const float*)d_in[2];   // [64,2]
    float* out = (float*)d_out;                // [B]

    rnn_scan_kernel<<<dim3(BB), dim3(64), 256, stream>>>(x, Wh, Wx, out);
}